// Round 5
// baseline (375.086 us; speedup 1.0000x reference)
//
#include <hip/hip_runtime.h>
#include <cstdint>

#define SEQ     8192
#define BATCH   4
#define NHEAD   8
#define NTOK    (BATCH*SEQ)   // 32768 tokens, D_MODEL=512

typedef __bf16 bf16x8 __attribute__((ext_vector_type(8)));
typedef float  floatx4 __attribute__((ext_vector_type(4)));

static __device__ __forceinline__ float b2f(uint16_t h) {
    return __uint_as_float(((uint32_t)h) << 16);
}
static __device__ __forceinline__ uint16_t f2b(float f) {
    uint32_t u = __float_as_uint(f);
    u += 0x7fffu + ((u >> 16) & 1u);      // round-to-nearest-even
    return (uint16_t)(u >> 16);
}

// ---------------------------------------------------------------------------
// W (fp32 [k][n] 512x512) -> W^T (bf16 [n][k]) for q,k,v,o. grid (8,8,4).
// ---------------------------------------------------------------------------
__global__ __launch_bounds__(256) void convert_w(
    const float* __restrict__ Wq, const float* __restrict__ Wk,
    const float* __restrict__ Wv, const float* __restrict__ Wo,
    uint16_t* __restrict__ out)   // 4 mats contiguous, 262144 elems each
{
    const int z = blockIdx.z;
    const float* W = (z == 0) ? Wq : (z == 1) ? Wk : (z == 2) ? Wv : Wo;
    uint16_t* o = out + (size_t)z * 262144;
    const int n0 = blockIdx.x * 64, k0 = blockIdx.y * 64;
    __shared__ uint16_t tl[64][64];
    const int t = threadIdx.x;
    const int r  = t >> 4;
    const int c4 = (t & 15) * 4;
    #pragma unroll
    for (int s = 0; s < 4; ++s) {
        const int k = r + s * 16;
        float4 f = *(const float4*)(W + (size_t)(k0 + k) * 512 + n0 + c4);
        tl[c4 + 0][k] = f2b(f.x); tl[c4 + 1][k] = f2b(f.y);
        tl[c4 + 2][k] = f2b(f.z); tl[c4 + 3][k] = f2b(f.w);
    }
    __syncthreads();
    const int n  = t >> 2;
    const int kk = (t & 3) * 16;
    uint4* dst = (uint4*)(o + (size_t)(n0 + n) * 512 + k0 + kk);
    dst[0] = *(const uint4*)&tl[n][kk];
    dst[1] = *(const uint4*)&tl[n][kk + 8];
}

// ---------------------------------------------------------------------------
// Fused QKV projection, 128x128 tile, BK=32, 4 waves 2x2, 4x4 frags/wave.
// Flat grid 3072, XCD-swizzled: id = 8*(12*(s>>3)+j) + (s&7) so the 12
// blocks sharing X m-stripe s land on one XCD (round-robin id%8) -> X stripe
// fetched once per XCD L2. j = proj*4 + n-tile.
// A: fp32->bf16 staged to padded LDS (stride 40 u16 = 20 banks, conflict-free).
// B: fragments read DIRECT from global W^T (L2-resident, no LDS, no conflicts).
// MFMA layouts (m89/m120): A[m=lane&15][k=quad*8+j]; B^T[n][k] lane=n;
// D: row=quad*4+r, col=lane&15.
// ---------------------------------------------------------------------------
__global__ __launch_bounds__(256) void qkv128(
    const float* __restrict__ X,
    const uint16_t* __restrict__ Wt,   // 3 mats [n][k] bf16
    const float* __restrict__ bq_, const float* __restrict__ bk_,
    const float* __restrict__ bv_,
    uint16_t* __restrict__ outQ, uint16_t* __restrict__ outK,
    uint16_t* __restrict__ outV)
{
    const int id = blockIdx.x;
    const int c  = id & 7;
    const int r_ = id >> 3;
    const int j_ = r_ % 12;
    const int s  = (r_ / 12) * 8 + c;     // m-stripe 0..255
    const int proj = j_ >> 2;
    const int n0   = (j_ & 3) * 128;
    const int m0   = s * 128;

    const uint16_t* W = Wt + (size_t)proj * 262144;
    const float* bias = (proj == 0) ? bq_ : (proj == 1) ? bk_ : bv_;
    uint16_t* out     = (proj == 0) ? outQ : (proj == 1) ? outK : outV;
    const int act = (proj < 2);

    __shared__ uint16_t sA[128 * 40];
    const int t = threadIdx.x;
    const int wave = t >> 6, lane = t & 63, quad = lane >> 4, lrow = lane & 15;
    const int wm = (wave & 1) * 64, wn = (wave >> 1) * 64;
    const int sr = t >> 2;             // staging row 0..63
    const int sc = (t & 3) * 8;        // staging k-offset

    floatx4 acc[4][4] = {};

    for (int k0 = 0; k0 < 512; k0 += 32) {
        // B fragments straight from global (L2 hit after first stripe)
        bf16x8 bfr[4];
        #pragma unroll
        for (int j = 0; j < 4; ++j)
            bfr[j] = *(const bf16x8*)(W + (size_t)(wn + j * 16 + lrow) * 512 + k0 + quad * 8);
        // A tile fp32 -> bf16 -> padded LDS
        const float* gA = X + (size_t)(m0 + sr) * 512 + k0 + sc;
        uint4 a0, a1;
        {
            float4 f0 = *(const float4*)gA;
            float4 f1 = *(const float4*)(gA + 4);
            float4 f2 = *(const float4*)(gA + 64 * 512);
            float4 f3 = *(const float4*)(gA + 64 * 512 + 4);
            uint16_t* p0 = (uint16_t*)&a0;
            uint16_t* p1 = (uint16_t*)&a1;
            p0[0]=f2b(f0.x); p0[1]=f2b(f0.y); p0[2]=f2b(f0.z); p0[3]=f2b(f0.w);
            p0[4]=f2b(f1.x); p0[5]=f2b(f1.y); p0[6]=f2b(f1.z); p0[7]=f2b(f1.w);
            p1[0]=f2b(f2.x); p1[1]=f2b(f2.y); p1[2]=f2b(f2.z); p1[3]=f2b(f2.w);
            p1[4]=f2b(f3.x); p1[5]=f2b(f3.y); p1[6]=f2b(f3.z); p1[7]=f2b(f3.w);
        }
        *(uint4*)(sA + sr * 40 + sc) = a0;
        *(uint4*)(sA + (sr + 64) * 40 + sc) = a1;
        __syncthreads();
        bf16x8 af[4];
        #pragma unroll
        for (int i = 0; i < 4; ++i)
            af[i] = *(const bf16x8*)(sA + (wm + i * 16 + lrow) * 40 + quad * 8);
        #pragma unroll
        for (int i = 0; i < 4; ++i)
            #pragma unroll
            for (int j = 0; j < 4; ++j)
                acc[i][j] = __builtin_amdgcn_mfma_f32_16x16x32_bf16(af[i], bfr[j], acc[i][j], 0, 0, 0);
        __syncthreads();
    }

    #pragma unroll
    for (int j = 0; j < 4; ++j) {
        const int col = n0 + wn + j * 16 + lrow;
        const float bb = bias[col];
        #pragma unroll
        for (int i = 0; i < 4; ++i) {
            #pragma unroll
            for (int r = 0; r < 4; ++r) {
                const int row = m0 + wm + i * 16 + quad * 4 + r;
                float v = acc[i][j][r] + bb;
                if (act) v = (v > 0.0f) ? (v + 1.0f) : __expf(v);  // elu+1
                out[(size_t)row * 512 + col] = f2b(v);
            }
        }
    }
}

// ---------------------------------------------------------------------------
// Output projection, 128x128 tile. Flat grid 1024, XCD-swizzled:
// id = 8*(4*(s>>3)+j) + (s&7). A bf16 staged to padded LDS; B (Wo^T) direct
// from global. out = A*Wo + bo + resid(fp32).
// ---------------------------------------------------------------------------
__global__ __launch_bounds__(256) void gemm_out128(
    const uint16_t* __restrict__ A,
    const uint16_t* __restrict__ Wt,   // [n][k] bf16
    const float* __restrict__ bias,
    const float* __restrict__ resid,
    uint16_t* __restrict__ out)
{
    const int id = blockIdx.x;
    const int c  = id & 7;
    const int r_ = id >> 3;
    const int j_ = r_ & 3;
    const int s  = (r_ >> 2) * 8 + c;
    const int n0 = j_ * 128;
    const int m0 = s * 128;

    __shared__ uint16_t sA[128 * 40];
    const int t = threadIdx.x;
    const int wave = t >> 6, lane = t & 63, quad = lane >> 4, lrow = lane & 15;
    const int wm = (wave & 1) * 64, wn = (wave >> 1) * 64;
    const int sr = t >> 2;
    const int sc = (t & 3) * 8;

    floatx4 acc[4][4] = {};

    for (int k0 = 0; k0 < 512; k0 += 32) {
        bf16x8 bfr[4];
        #pragma unroll
        for (int j = 0; j < 4; ++j)
            bfr[j] = *(const bf16x8*)(Wt + (size_t)(wn + j * 16 + lrow) * 512 + k0 + quad * 8);
        const uint16_t* gA = A + (size_t)(m0 + sr) * 512 + k0 + sc;
        uint4 a0 = *(const uint4*)gA;
        uint4 a1 = *(const uint4*)(gA + 64 * 512);
        *(uint4*)(sA + sr * 40 + sc) = a0;
        *(uint4*)(sA + (sr + 64) * 40 + sc) = a1;
        __syncthreads();
        bf16x8 af[4];
        #pragma unroll
        for (int i = 0; i < 4; ++i)
            af[i] = *(const bf16x8*)(sA + (wm + i * 16 + lrow) * 40 + quad * 8);
        #pragma unroll
        for (int i = 0; i < 4; ++i)
            #pragma unroll
            for (int j = 0; j < 4; ++j)
                acc[i][j] = __builtin_amdgcn_mfma_f32_16x16x32_bf16(af[i], bfr[j], acc[i][j], 0, 0, 0);
        __syncthreads();
    }

    #pragma unroll
    for (int j = 0; j < 4; ++j) {
        const int col = n0 + wn + j * 16 + lrow;
        const float bb = bias[col];
        #pragma unroll
        for (int i = 0; i < 4; ++i) {
            #pragma unroll
            for (int r = 0; r < 4; ++r) {
                const int row = m0 + wm + i * 16 + quad * 4 + r;
                float v = acc[i][j][r] + bb + resid[(size_t)row * 512 + col];
                out[(size_t)row * 512 + col] = f2b(v);
            }
        }
    }
}

// ---------------------------------------------------------------------------
// KV[bh][d][m] += sum_n k[n][d]*v[n][m]  (MFMA: C = K^T * V, split-K atomics)
// KSUM[bh][d]  += sum_n k[n][d]          (MFMA with all-ones B)
// grid (16 chunks of 512 tokens, H, B).
// ---------------------------------------------------------------------------
__global__ __launch_bounds__(256) void kv_accum(
    const uint16_t* __restrict__ K,
    const uint16_t* __restrict__ V,
    float* __restrict__ KV,
    float* __restrict__ KSUM)
{
    const int chunk = blockIdx.x;
    const int h     = blockIdx.y;
    const int b     = blockIdx.z;
    const int t    = threadIdx.x;
    const int wv   = t >> 6;
    const int lane = t & 63;
    const int quad = lane >> 4;
    const int lrow = lane & 15;

    __shared__ uint16_t kt[64 * 72];   // [d][tok]
    __shared__ uint16_t vt[64 * 72];   // [m][tok]

    floatx4 acc[4] = {};
    floatx4 accS = {};
    union { uint16_t u[8]; bf16x8 v; } one_u;
    #pragma unroll
    for (int j = 0; j < 8; ++j) one_u.u[j] = 0x3F80;  // bf16 1.0
    const bf16x8 ones = one_u.v;

    const size_t base = ((size_t)(b * SEQ + chunk * 512)) * 512 + h * 64;

    for (int n0 = 0; n0 < 512; n0 += 64) {
        #pragma unroll
        for (int s = 0; s < 2; ++s) {
            const int i   = t + 256 * s;
            const int tok = i >> 3;
            const int d0  = (i & 7) * 8;
            uint4 kq = *(const uint4*)(K + base + (size_t)(n0 + tok) * 512 + d0);
            const uint16_t* kp = (const uint16_t*)&kq;
            #pragma unroll
            for (int j = 0; j < 8; ++j) kt[(d0 + j) * 72 + tok] = kp[j];
            uint4 vq = *(const uint4*)(V + base + (size_t)(n0 + tok) * 512 + d0);
            const uint16_t* vp = (const uint16_t*)&vq;
            #pragma unroll
            for (int j = 0; j < 8; ++j) vt[(d0 + j) * 72 + tok] = vp[j];
        }
        __syncthreads();
        #pragma unroll
        for (int ks = 0; ks < 2; ++ks) {
            bf16x8 af = *(const bf16x8*)(kt + (wv * 16 + lrow) * 72 + ks * 32 + quad * 8);
            accS = __builtin_amdgcn_mfma_f32_16x16x32_bf16(af, ones, accS, 0, 0, 0);
            #pragma unroll
            for (int nt = 0; nt < 4; ++nt) {
                bf16x8 bf = *(const bf16x8*)(vt + (nt * 16 + lrow) * 72 + ks * 32 + quad * 8);
                acc[nt] = __builtin_amdgcn_mfma_f32_16x16x32_bf16(af, bf, acc[nt], 0, 0, 0);
            }
        }
        __syncthreads();
    }

    float* kvp = KV + (size_t)(b * NHEAD + h) * 4096;
    #pragma unroll
    for (int nt = 0; nt < 4; ++nt) {
        const int m = nt * 16 + lrow;
        #pragma unroll
        for (int r = 0; r < 4; ++r) {
            const int d = wv * 16 + quad * 4 + r;
            atomicAdd(kvp + d * 64 + m, acc[nt][r]);
        }
    }
    if (lrow == 0) {
        float* kp = KSUM + (size_t)(b * NHEAD + h) * 64;
        #pragma unroll
        for (int r = 0; r < 4; ++r)
            atomicAdd(kp + wv * 16 + quad * 4 + r, accS[r]);
    }
}

// ---------------------------------------------------------------------------
// out[n][h*64+m] = (sum_d q[n][d]*KV[d][m]) / max(sum_d q[n][d]*ksum[d],1e-6)
// grid (NTOK/64, H).
// ---------------------------------------------------------------------------
__global__ __launch_bounds__(256) void attn_apply(
    const uint16_t* __restrict__ Q,
    const float* __restrict__ KVg,
    const float* __restrict__ KSg,
    uint16_t* __restrict__ OUT)
{
    const int h    = blockIdx.y;
    const int tok0 = blockIdx.x * 64;
    const int b    = tok0 >> 13;       // /8192, blocks never straddle batches
    const int t    = threadIdx.x;
    const int wv   = t >> 6;
    const int lane = t & 63;
    const int quad = lane >> 4;
    const int lrow = lane & 15;

    __shared__ uint16_t bt[64 * 72];   // [m][d] = KV^T, bf16
    __shared__ uint16_t ksb[64];

    const float* kvp = KVg + (size_t)(b * NHEAD + h) * 4096;
    #pragma unroll
    for (int s = 0; s < 16; ++s) {
        const int e = t + 256 * s;     // e = d*64 + m
        const int d = e >> 6, m = e & 63;
        bt[m * 72 + d] = f2b(kvp[e]);
    }
    if (t < 64) ksb[t] = f2b(KSg[(size_t)(b * NHEAD + h) * 64 + t]);
    __syncthreads();

    floatx4 acc[4] = {};
    floatx4 accN = {};
    const uint16_t* qrow = Q + (size_t)(tok0 + wv * 16 + lrow) * 512 + h * 64 + quad * 8;
    #pragma unroll
    for (int ks = 0; ks < 2; ++ks) {
        bf16x8 af = *(const bf16x8*)(qrow + ks * 32);
        bf16x8 bks = *(const bf16x8*)(ksb + ks * 32 + quad * 8);
        accN = __builtin_amdgcn_mfma_f32_16x16x32_bf16(af, bks, accN, 0, 0, 0);
        #pragma unroll
        for (int nt = 0; nt < 4; ++nt) {
            bf16x8 bf = *(const bf16x8*)(bt + (nt * 16 + lrow) * 72 + ks * 32 + quad * 8);
            acc[nt] = __builtin_amdgcn_mfma_f32_16x16x32_bf16(af, bf, acc[nt], 0, 0, 0);
        }
    }

    #pragma unroll
    for (int r = 0; r < 4; ++r) {
        const float inv = 1.0f / fmaxf(accN[r], 1e-6f);
        const int tok = tok0 + wv * 16 + quad * 4 + r;
        #pragma unroll
        for (int nt = 0; nt < 4; ++nt)
            OUT[(size_t)tok * 512 + h * 64 + nt * 16 + lrow] = f2b(acc[nt][r] * inv);
    }
}

// rowwise LayerNorm over 512: Z bf16, gamma/beta fp32, OUT fp32.
__global__ __launch_bounds__(256) void ln_fused(
    const uint16_t* __restrict__ Z,
    const float* __restrict__ gamma,
    const float* __restrict__ beta,
    float* __restrict__ OUT)
{
    const size_t row = blockIdx.x;
    const int t = threadIdx.x;
    const uint16_t* zp = Z + row * 512;
    uint32_t u = *(const uint32_t*)(zp + t * 2);
    float v0 = b2f((uint16_t)(u & 0xffff));
    float v1 = b2f((uint16_t)(u >> 16));
    float s = v0 + v1;
    float s2 = v0 * v0 + v1 * v1;
    #pragma unroll
    for (int off = 32; off > 0; off >>= 1) {
        s  += __shfl_down(s, off, 64);
        s2 += __shfl_down(s2, off, 64);
    }
    __shared__ float sb[4], sb2[4];
    const int wv = t >> 6, lane = t & 63;
    if (lane == 0) { sb[wv] = s; sb2[wv] = s2; }
    __syncthreads();
    const float tot  = sb[0] + sb[1] + sb[2] + sb[3];
    const float tot2 = sb2[0] + sb2[1] + sb2[2] + sb2[3];
    const float mean = tot * (1.0f / 512.0f);
    const float var  = tot2 * (1.0f / 512.0f) - mean * mean;
    const float inv  = rsqrtf(var + 1e-5f);
    const float2 g  = *(const float2*)(gamma + t * 2);
    const float2 bb = *(const float2*)(beta + t * 2);
    float2 o;
    o.x = (v0 - mean) * inv * g.x + bb.x;
    o.y = (v1 - mean) * inv * g.y + bb.y;
    *(float2*)(OUT + row * 512 + t * 2) = o;
}

extern "C" void kernel_launch(void* const* d_in, const int* in_sizes, int n_in,
                              void* d_out, int out_size, void* d_ws, size_t ws_size,
                              hipStream_t stream)
{
    (void)in_sizes; (void)n_in; (void)out_size; (void)ws_size;
    const float* x     = (const float*)d_in[0];
    const float* Wq    = (const float*)d_in[1];
    const float* bq    = (const float*)d_in[2];
    const float* Wk    = (const float*)d_in[3];
    const float* bk    = (const float*)d_in[4];
    const float* Wv    = (const float*)d_in[5];
    const float* bv    = (const float*)d_in[6];
    const float* Wo    = (const float*)d_in[7];
    const float* bo    = (const float*)d_in[8];
    const float* gamma = (const float*)d_in[9];
    const float* beta  = (const float*)d_in[10];

    // ws layout (~34.6 MiB): KV(512K) + KSUM(8K) + Wt(2M) + phiQ(32M).
    // d_out (fp32, 64 MiB) doubles as bf16 scratch until the final LN write:
    //   low half: phiK -> attn ; high half: vbuf.
    uint8_t* ws = (uint8_t*)d_ws;
    float*    KV   = (float*)ws;
    float*    KSUM = (float*)(ws + (size_t)32 * 4096 * 4);
    uint16_t* Wt   = (uint16_t*)(ws + (size_t)32 * 4096 * 4 + 32 * 64 * 4);
    uint16_t* phiQ = (uint16_t*)(ws + (size_t)32 * 4096 * 4 + 32 * 64 * 4
                                    + (size_t)4 * 262144 * 2);
    uint16_t* phiK = (uint16_t*)d_out;
    uint16_t* vbuf = (uint16_t*)d_out + (size_t)NTOK * 512;
    uint16_t* attn = phiK;   // phiK dead after kv_accum
    uint16_t* zbuf = phiQ;   // phiQ dead after attn_apply

    hipMemsetAsync(ws, 0, (size_t)32 * 4096 * 4 + 32 * 64 * 4, stream);

    dim3 blk(256);
    convert_w<<<dim3(8, 8, 4), blk, 0, stream>>>(Wq, Wk, Wv, Wo, Wt);
    qkv128<<<dim3(3072), blk, 0, stream>>>(
        x, Wt, bq, bk, bv, phiQ, phiK, vbuf);
    kv_accum<<<dim3(16, NHEAD, BATCH), blk, 0, stream>>>(phiK, vbuf, KV, KSUM);
    attn_apply<<<dim3(NTOK / 64, NHEAD), blk, 0, stream>>>(phiQ, KV, KSUM, attn);
    gemm_out128<<<dim3(1024), blk, 0, stream>>>(
        attn, Wt + (size_t)3 * 262144, bo, x, zbuf);
    ln_fused<<<NTOK, blk, 0, stream>>>(zbuf, gamma, beta, (float*)d_out);
}

// Round 6
// 336.123 us; speedup vs baseline: 1.1159x; 1.1159x over previous
//
#include <hip/hip_runtime.h>
#include <cstdint>

#define SEQ     8192
#define BATCH   4
#define NHEAD   8
#define NTOK    (BATCH*SEQ)   // 32768 tokens, D_MODEL=512

typedef __bf16 bf16x8 __attribute__((ext_vector_type(8)));
typedef float  floatx4 __attribute__((ext_vector_type(4)));

static __device__ __forceinline__ float b2f(uint16_t h) {
    return __uint_as_float(((uint32_t)h) << 16);
}
static __device__ __forceinline__ uint16_t f2b(float f) {
    uint32_t u = __float_as_uint(f);
    u += 0x7fffu + ((u >> 16) & 1u);      // round-to-nearest-even
    return (uint16_t)(u >> 16);
}

// async global->LDS, 16 B per lane. LDS dest must be wave-uniform base + lane*16.
static __device__ __forceinline__ void async_copy16(const uint16_t* g, uint16_t* l) {
#if __has_builtin(__builtin_amdgcn_global_load_lds)
    __builtin_amdgcn_global_load_lds(
        (const __attribute__((address_space(1))) void*)g,
        (__attribute__((address_space(3))) void*)l, 16, 0, 0);
#else
    *(uint4*)l = *(const uint4*)g;
#endif
}

// ---------------------------------------------------------------------------
// W (fp32 [k][n] 512x512) -> W^T (bf16 [n][k]) for q,k,v,o. grid (8,8,4).
// ---------------------------------------------------------------------------
__global__ __launch_bounds__(256) void convert_w(
    const float* __restrict__ Wq, const float* __restrict__ Wk,
    const float* __restrict__ Wv, const float* __restrict__ Wo,
    uint16_t* __restrict__ out)   // 4 mats contiguous, 262144 elems each
{
    const int z = blockIdx.z;
    const float* W = (z == 0) ? Wq : (z == 1) ? Wk : (z == 2) ? Wv : Wo;
    uint16_t* o = out + (size_t)z * 262144;
    const int n0 = blockIdx.x * 64, k0 = blockIdx.y * 64;
    __shared__ uint16_t tl[64][64];
    const int t = threadIdx.x;
    const int r  = t >> 4;
    const int c4 = (t & 15) * 4;
    #pragma unroll
    for (int s = 0; s < 4; ++s) {
        const int k = r + s * 16;
        float4 f = *(const float4*)(W + (size_t)(k0 + k) * 512 + n0 + c4);
        tl[c4 + 0][k] = f2b(f.x); tl[c4 + 1][k] = f2b(f.y);
        tl[c4 + 2][k] = f2b(f.z); tl[c4 + 3][k] = f2b(f.w);
    }
    __syncthreads();
    const int n  = t >> 2;
    const int kk = (t & 3) * 16;
    uint4* dst = (uint4*)(o + (size_t)(n0 + n) * 512 + k0 + kk);
    dst[0] = *(const uint4*)&tl[n][kk];
    dst[1] = *(const uint4*)&tl[n][kk + 8];
}

// ---------------------------------------------------------------------------
// Fused QKV projection, 128x128 tile, BK=32, 4 waves 2x2, 4x4 frags/wave.
// Flat grid 3072, XCD-swizzled: id = 8*(12*(s>>3)+j) + (s&7) so the 12
// blocks sharing X m-stripe s land on one XCD -> X stripe fetched once per L2.
// A: fp32->bf16 staged to padded LDS (stride 40 u16, conflict-free frag reads).
// B: W^T bf16 async-staged to LDS (m97-style, unpadded — off the latency path).
// MFMA layouts (m89/m120): A[m=lane&15][k=quad*8+j]; B^T[n][k] lane=n;
// D: row=quad*4+r, col=lane&15.
// ---------------------------------------------------------------------------
__global__ __launch_bounds__(256) void qkv128(
    const float* __restrict__ X,
    const uint16_t* __restrict__ Wt,   // 3 mats [n][k] bf16
    const float* __restrict__ bq_, const float* __restrict__ bk_,
    const float* __restrict__ bv_,
    uint16_t* __restrict__ outQ, uint16_t* __restrict__ outK,
    uint16_t* __restrict__ outV)
{
    const int id = blockIdx.x;
    const int c  = id & 7;
    const int r_ = id >> 3;
    const int j_ = r_ % 12;
    const int s  = (r_ / 12) * 8 + c;     // m-stripe 0..255
    const int proj = j_ >> 2;
    const int n0   = (j_ & 3) * 128;
    const int m0   = s * 128;

    const uint16_t* W = Wt + (size_t)proj * 262144;
    const float* bias = (proj == 0) ? bq_ : (proj == 1) ? bk_ : bv_;
    uint16_t* out     = (proj == 0) ? outQ : (proj == 1) ? outK : outV;
    const int act = (proj < 2);

    __shared__ uint16_t sA[128 * 40];  // padded
    __shared__ uint16_t sB[128 * 32];  // unpadded (async constraint)
    const int t = threadIdx.x;
    const int wave = t >> 6, lane = t & 63, quad = lane >> 4, lrow = lane & 15;
    const int wm = (wave & 1) * 64, wn = (wave >> 1) * 64;
    const int sr = t >> 2;             // staging row 0..63
    const int sc = (t & 3) * 8;        // staging k-offset

    floatx4 acc[4][4] = {};

    for (int k0 = 0; k0 < 512; k0 += 32) {
        // B: async global->LDS (2 x 16 B per thread), issued first
        const uint16_t* gB = W + (size_t)(n0 + sr) * 512 + k0 + sc;
        async_copy16(gB, sB + t * 8);
        async_copy16(gB + 64 * 512, sB + (t + 256) * 8);
        // A: fp32 -> bf16 -> padded LDS
        const float* gA = X + (size_t)(m0 + sr) * 512 + k0 + sc;
        uint4 a0, a1;
        {
            float4 f0 = *(const float4*)gA;
            float4 f1 = *(const float4*)(gA + 4);
            float4 f2 = *(const float4*)(gA + 64 * 512);
            float4 f3 = *(const float4*)(gA + 64 * 512 + 4);
            uint16_t* p0 = (uint16_t*)&a0;
            uint16_t* p1 = (uint16_t*)&a1;
            p0[0]=f2b(f0.x); p0[1]=f2b(f0.y); p0[2]=f2b(f0.z); p0[3]=f2b(f0.w);
            p0[4]=f2b(f1.x); p0[5]=f2b(f1.y); p0[6]=f2b(f1.z); p0[7]=f2b(f1.w);
            p1[0]=f2b(f2.x); p1[1]=f2b(f2.y); p1[2]=f2b(f2.z); p1[3]=f2b(f2.w);
            p1[4]=f2b(f3.x); p1[5]=f2b(f3.y); p1[6]=f2b(f3.z); p1[7]=f2b(f3.w);
        }
        *(uint4*)(sA + sr * 40 + sc) = a0;
        *(uint4*)(sA + (sr + 64) * 40 + sc) = a1;
        __syncthreads();
        bf16x8 af[4], bfr[4];
        #pragma unroll
        for (int i = 0; i < 4; ++i)
            af[i] = *(const bf16x8*)(sA + (wm + i * 16 + lrow) * 40 + quad * 8);
        #pragma unroll
        for (int j = 0; j < 4; ++j)
            bfr[j] = *(const bf16x8*)(sB + (wn + j * 16 + lrow) * 32 + quad * 8);
        #pragma unroll
        for (int i = 0; i < 4; ++i)
            #pragma unroll
            for (int j = 0; j < 4; ++j)
                acc[i][j] = __builtin_amdgcn_mfma_f32_16x16x32_bf16(af[i], bfr[j], acc[i][j], 0, 0, 0);
        __syncthreads();
    }

    #pragma unroll
    for (int j = 0; j < 4; ++j) {
        const int col = n0 + wn + j * 16 + lrow;
        const float bb = bias[col];
        #pragma unroll
        for (int i = 0; i < 4; ++i) {
            #pragma unroll
            for (int r = 0; r < 4; ++r) {
                const int row = m0 + wm + i * 16 + quad * 4 + r;
                float v = acc[i][j][r] + bb;
                if (act) v = (v > 0.0f) ? (v + 1.0f) : __expf(v);  // elu+1
                out[(size_t)row * 512 + col] = f2b(v);
            }
        }
    }
}

// ---------------------------------------------------------------------------
// Output projection, 128x128 tile. Flat grid 1024, XCD-swizzled:
// id = 8*(4*(s>>3)+j) + (s&7). A (bf16) and B (Wo^T bf16) both async-staged.
// out = A*Wo + bo + resid(fp32).
// ---------------------------------------------------------------------------
__global__ __launch_bounds__(256) void gemm_out128(
    const uint16_t* __restrict__ A,
    const uint16_t* __restrict__ Wt,   // [n][k] bf16
    const float* __restrict__ bias,
    const float* __restrict__ resid,
    uint16_t* __restrict__ out)
{
    const int id = blockIdx.x;
    const int c  = id & 7;
    const int r_ = id >> 3;
    const int j_ = r_ & 3;
    const int s  = (r_ >> 2) * 8 + c;
    const int n0 = j_ * 128;
    const int m0 = s * 128;

    __shared__ uint16_t sA[128 * 32];
    __shared__ uint16_t sB[128 * 32];
    const int t = threadIdx.x;
    const int wave = t >> 6, lane = t & 63, quad = lane >> 4, lrow = lane & 15;
    const int wm = (wave & 1) * 64, wn = (wave >> 1) * 64;
    const int sr = t >> 2;
    const int sc = (t & 3) * 8;

    floatx4 acc[4][4] = {};

    for (int k0 = 0; k0 < 512; k0 += 32) {
        const uint16_t* gA = A + (size_t)(m0 + sr) * 512 + k0 + sc;
        async_copy16(gA, sA + t * 8);
        async_copy16(gA + 64 * 512, sA + (t + 256) * 8);
        const uint16_t* gB = Wt + (size_t)(n0 + sr) * 512 + k0 + sc;
        async_copy16(gB, sB + t * 8);
        async_copy16(gB + 64 * 512, sB + (t + 256) * 8);
        __syncthreads();
        bf16x8 af[4], bfr[4];
        #pragma unroll
        for (int i = 0; i < 4; ++i)
            af[i] = *(const bf16x8*)(sA + (wm + i * 16 + lrow) * 32 + quad * 8);
        #pragma unroll
        for (int j = 0; j < 4; ++j)
            bfr[j] = *(const bf16x8*)(sB + (wn + j * 16 + lrow) * 32 + quad * 8);
        #pragma unroll
        for (int i = 0; i < 4; ++i)
            #pragma unroll
            for (int j = 0; j < 4; ++j)
                acc[i][j] = __builtin_amdgcn_mfma_f32_16x16x32_bf16(af[i], bfr[j], acc[i][j], 0, 0, 0);
        __syncthreads();
    }

    #pragma unroll
    for (int j = 0; j < 4; ++j) {
        const int col = n0 + wn + j * 16 + lrow;
        const float bb = bias[col];
        #pragma unroll
        for (int i = 0; i < 4; ++i) {
            #pragma unroll
            for (int r = 0; r < 4; ++r) {
                const int row = m0 + wm + i * 16 + quad * 4 + r;
                float v = acc[i][j][r] + bb + resid[(size_t)row * 512 + col];
                out[(size_t)row * 512 + col] = f2b(v);
            }
        }
    }
}

// ---------------------------------------------------------------------------
// KV[bh][d][m] += sum_n k[n][d]*v[n][m]  (MFMA: C = K^T * V, split-K atomics)
// KSUM[bh][d]  += sum_n k[n][d]          (MFMA with all-ones B)
// grid (16 chunks of 512 tokens, H, B).
// ---------------------------------------------------------------------------
__global__ __launch_bounds__(256) void kv_accum(
    const uint16_t* __restrict__ K,
    const uint16_t* __restrict__ V,
    float* __restrict__ KV,
    float* __restrict__ KSUM)
{
    const int chunk = blockIdx.x;
    const int h     = blockIdx.y;
    const int b     = blockIdx.z;
    const int t    = threadIdx.x;
    const int wv   = t >> 6;
    const int lane = t & 63;
    const int quad = lane >> 4;
    const int lrow = lane & 15;

    __shared__ uint16_t kt[64 * 72];   // [d][tok]
    __shared__ uint16_t vt[64 * 72];   // [m][tok]

    floatx4 acc[4] = {};
    floatx4 accS = {};
    union { uint16_t u[8]; bf16x8 v; } one_u;
    #pragma unroll
    for (int j = 0; j < 8; ++j) one_u.u[j] = 0x3F80;  // bf16 1.0
    const bf16x8 ones = one_u.v;

    const size_t base = ((size_t)(b * SEQ + chunk * 512)) * 512 + h * 64;

    for (int n0 = 0; n0 < 512; n0 += 64) {
        #pragma unroll
        for (int s = 0; s < 2; ++s) {
            const int i   = t + 256 * s;
            const int tok = i >> 3;
            const int d0  = (i & 7) * 8;
            uint4 kq = *(const uint4*)(K + base + (size_t)(n0 + tok) * 512 + d0);
            const uint16_t* kp = (const uint16_t*)&kq;
            #pragma unroll
            for (int j = 0; j < 8; ++j) kt[(d0 + j) * 72 + tok] = kp[j];
            uint4 vq = *(const uint4*)(V + base + (size_t)(n0 + tok) * 512 + d0);
            const uint16_t* vp = (const uint16_t*)&vq;
            #pragma unroll
            for (int j = 0; j < 8; ++j) vt[(d0 + j) * 72 + tok] = vp[j];
        }
        __syncthreads();
        #pragma unroll
        for (int ks = 0; ks < 2; ++ks) {
            bf16x8 af = *(const bf16x8*)(kt + (wv * 16 + lrow) * 72 + ks * 32 + quad * 8);
            accS = __builtin_amdgcn_mfma_f32_16x16x32_bf16(af, ones, accS, 0, 0, 0);
            #pragma unroll
            for (int nt = 0; nt < 4; ++nt) {
                bf16x8 bf = *(const bf16x8*)(vt + (nt * 16 + lrow) * 72 + ks * 32 + quad * 8);
                acc[nt] = __builtin_amdgcn_mfma_f32_16x16x32_bf16(af, bf, acc[nt], 0, 0, 0);
            }
        }
        __syncthreads();
    }

    float* kvp = KV + (size_t)(b * NHEAD + h) * 4096;
    #pragma unroll
    for (int nt = 0; nt < 4; ++nt) {
        const int m = nt * 16 + lrow;
        #pragma unroll
        for (int r = 0; r < 4; ++r) {
            const int d = wv * 16 + quad * 4 + r;
            atomicAdd(kvp + d * 64 + m, acc[nt][r]);
        }
    }
    if (lrow == 0) {
        float* kp = KSUM + (size_t)(b * NHEAD + h) * 64;
        #pragma unroll
        for (int r = 0; r < 4; ++r)
            atomicAdd(kp + wv * 16 + quad * 4 + r, accS[r]);
    }
}

// ---------------------------------------------------------------------------
// out[n][h*64+m] = (sum_d q[n][d]*KV[d][m]) / max(sum_d q[n][d]*ksum[d],1e-6)
// grid (NTOK/64, H).
// ---------------------------------------------------------------------------
__global__ __launch_bounds__(256) void attn_apply(
    const uint16_t* __restrict__ Q,
    const float* __restrict__ KVg,
    const float* __restrict__ KSg,
    uint16_t* __restrict__ OUT)
{
    const int h    = blockIdx.y;
    const int tok0 = blockIdx.x * 64;
    const int b    = tok0 >> 13;       // /8192, blocks never straddle batches
    const int t    = threadIdx.x;
    const int wv   = t >> 6;
    const int lane = t & 63;
    const int quad = lane >> 4;
    const int lrow = lane & 15;

    __shared__ uint16_t bt[64 * 72];   // [m][d] = KV^T, bf16
    __shared__ uint16_t ksb[64];

    const float* kvp = KVg + (size_t)(b * NHEAD + h) * 4096;
    #pragma unroll
    for (int s = 0; s < 16; ++s) {
        const int e = t + 256 * s;     // e = d*64 + m
        const int d = e >> 6, m = e & 63;
        bt[m * 72 + d] = f2b(kvp[e]);
    }
    if (t < 64) ksb[t] = f2b(KSg[(size_t)(b * NHEAD + h) * 64 + t]);
    __syncthreads();

    floatx4 acc[4] = {};
    floatx4 accN = {};
    const uint16_t* qrow = Q + (size_t)(tok0 + wv * 16 + lrow) * 512 + h * 64 + quad * 8;
    #pragma unroll
    for (int ks = 0; ks < 2; ++ks) {
        bf16x8 af = *(const bf16x8*)(qrow + ks * 32);
        bf16x8 bks = *(const bf16x8*)(ksb + ks * 32 + quad * 8);
        accN = __builtin_amdgcn_mfma_f32_16x16x32_bf16(af, bks, accN, 0, 0, 0);
        #pragma unroll
        for (int nt = 0; nt < 4; ++nt) {
            bf16x8 bf = *(const bf16x8*)(bt + (nt * 16 + lrow) * 72 + ks * 32 + quad * 8);
            acc[nt] = __builtin_amdgcn_mfma_f32_16x16x32_bf16(af, bf, acc[nt], 0, 0, 0);
        }
    }

    #pragma unroll
    for (int r = 0; r < 4; ++r) {
        const float inv = 1.0f / fmaxf(accN[r], 1e-6f);
        const int tok = tok0 + wv * 16 + quad * 4 + r;
        #pragma unroll
        for (int nt = 0; nt < 4; ++nt)
            OUT[(size_t)tok * 512 + h * 64 + nt * 16 + lrow] = f2b(acc[nt][r] * inv);
    }
}

// rowwise LayerNorm over 512: Z bf16, gamma/beta fp32, OUT fp32.
__global__ __launch_bounds__(256) void ln_fused(
    const uint16_t* __restrict__ Z,
    const float* __restrict__ gamma,
    const float* __restrict__ beta,
    float* __restrict__ OUT)
{
    const size_t row = blockIdx.x;
    const int t = threadIdx.x;
    const uint16_t* zp = Z + row * 512;
    uint32_t u = *(const uint32_t*)(zp + t * 2);
    float v0 = b2f((uint16_t)(u & 0xffff));
    float v1 = b2f((uint16_t)(u >> 16));
    float s = v0 + v1;
    float s2 = v0 * v0 + v1 * v1;
    #pragma unroll
    for (int off = 32; off > 0; off >>= 1) {
        s  += __shfl_down(s, off, 64);
        s2 += __shfl_down(s2, off, 64);
    }
    __shared__ float sb[4], sb2[4];
    const int wv = t >> 6, lane = t & 63;
    if (lane == 0) { sb[wv] = s; sb2[wv] = s2; }
    __syncthreads();
    const float tot  = sb[0] + sb[1] + sb[2] + sb[3];
    const float tot2 = sb2[0] + sb2[1] + sb2[2] + sb2[3];
    const float mean = tot * (1.0f / 512.0f);
    const float var  = tot2 * (1.0f / 512.0f) - mean * mean;
    const float inv  = rsqrtf(var + 1e-5f);
    const float2 g  = *(const float2*)(gamma + t * 2);
    const float2 bb = *(const float2*)(beta + t * 2);
    float2 o;
    o.x = (v0 - mean) * inv * g.x + bb.x;
    o.y = (v1 - mean) * inv * g.y + bb.y;
    *(float2*)(OUT + row * 512 + t * 2) = o;
}

extern "C" void kernel_launch(void* const* d_in, const int* in_sizes, int n_in,
                              void* d_out, int out_size, void* d_ws, size_t ws_size,
                              hipStream_t stream)
{
    (void)in_sizes; (void)n_in; (void)out_size; (void)ws_size;
    const float* x     = (const float*)d_in[0];
    const float* Wq    = (const float*)d_in[1];
    const float* bq    = (const float*)d_in[2];
    const float* Wk    = (const float*)d_in[3];
    const float* bk    = (const float*)d_in[4];
    const float* Wv    = (const float*)d_in[5];
    const float* bv    = (const float*)d_in[6];
    const float* Wo    = (const float*)d_in[7];
    const float* bo    = (const float*)d_in[8];
    const float* gamma = (const float*)d_in[9];
    const float* beta  = (const float*)d_in[10];

    // ws layout (~34.6 MiB): KV(512K) + KSUM(8K) + Wt(2M) + phiQ(32M).
    // d_out (fp32, 64 MiB) doubles as bf16 scratch until the final LN write:
    //   low half: phiK -> attn ; high half: vbuf.
    uint8_t* ws = (uint8_t*)d_ws;
    float*    KV   = (float*)ws;
    float*    KSUM = (float*)(ws + (size_t)32 * 4096 * 4);
    uint16_t* Wt   = (uint16_t*)(ws + (size_t)32 * 4096 * 4 + 32 * 64 * 4);
    uint16_t* phiQ = (uint16_t*)(ws + (size_t)32 * 4096 * 4 + 32 * 64 * 4
                                    + (size_t)4 * 262144 * 2);
    uint16_t* phiK = (uint16_t*)d_out;
    uint16_t* vbuf = (uint16_t*)d_out + (size_t)NTOK * 512;
    uint16_t* attn = phiK;   // phiK dead after kv_accum
    uint16_t* zbuf = phiQ;   // phiQ dead after attn_apply

    hipMemsetAsync(ws, 0, (size_t)32 * 4096 * 4 + 32 * 64 * 4, stream);

    dim3 blk(256);
    convert_w<<<dim3(8, 8, 4), blk, 0, stream>>>(Wq, Wk, Wv, Wo, Wt);
    qkv128<<<dim3(3072), blk, 0, stream>>>(
        x, Wt, bq, bk, bv, phiQ, phiK, vbuf);
    kv_accum<<<dim3(16, NHEAD, BATCH), blk, 0, stream>>>(phiK, vbuf, KV, KSUM);
    attn_apply<<<dim3(NTOK / 64, NHEAD), blk, 0, stream>>>(phiQ, KV, KSUM, attn);
    gemm_out128<<<dim3(1024), blk, 0, stream>>>(
        attn, Wt + (size_t)3 * 262144, bo, x, zbuf);
    ln_fused<<<NTOK, blk, 0, stream>>>(zbuf, gamma, beta, (float*)d_out);
}

// Round 7
// 312.472 us; speedup vs baseline: 1.2004x; 1.0757x over previous
//
#include <hip/hip_runtime.h>
#include <cstdint>

#define SEQ     8192
#define BATCH   4
#define NHEAD   8
#define NTOK    (BATCH*SEQ)   // 32768 tokens, D_MODEL=512

typedef __bf16 bf16x8 __attribute__((ext_vector_type(8)));
typedef float  floatx4 __attribute__((ext_vector_type(4)));

static __device__ __forceinline__ float b2f(uint16_t h) {
    return __uint_as_float(((uint32_t)h) << 16);
}
static __device__ __forceinline__ uint16_t f2b(float f) {
    uint32_t u = __float_as_uint(f);
    u += 0x7fffu + ((u >> 16) & 1u);      // round-to-nearest-even
    return (uint16_t)(u >> 16);
}

// async global->LDS, 16 B per lane. LDS dest must be wave-uniform base + lane*16.
static __device__ __forceinline__ void async_copy16(const uint16_t* g, uint16_t* l) {
#if __has_builtin(__builtin_amdgcn_global_load_lds)
    __builtin_amdgcn_global_load_lds(
        (const __attribute__((address_space(1))) void*)g,
        (__attribute__((address_space(3))) void*)l, 16, 0, 0);
#else
    *(uint4*)l = *(const uint4*)g;
#endif
}

// ---------------------------------------------------------------------------
// X fp32 -> bf16, streaming. 8 elems/thread. grid NTOK*512/(256*8)=8192.
// ---------------------------------------------------------------------------
__global__ __launch_bounds__(256) void convert_x(
    const float* __restrict__ X, uint16_t* __restrict__ Xb)
{
    const size_t i = ((size_t)blockIdx.x * 256 + threadIdx.x) * 8;
    float4 f0 = *(const float4*)(X + i);
    float4 f1 = *(const float4*)(X + i + 4);
    uint4 o;
    uint16_t* p = (uint16_t*)&o;
    p[0]=f2b(f0.x); p[1]=f2b(f0.y); p[2]=f2b(f0.z); p[3]=f2b(f0.w);
    p[4]=f2b(f1.x); p[5]=f2b(f1.y); p[6]=f2b(f1.z); p[7]=f2b(f1.w);
    *(uint4*)(Xb + i) = o;
}

// ---------------------------------------------------------------------------
// W (fp32 [k][n] 512x512) -> W^T (bf16 [n][k]) for q,k,v,o. grid (8,8,4).
// ---------------------------------------------------------------------------
__global__ __launch_bounds__(256) void convert_w(
    const float* __restrict__ Wq, const float* __restrict__ Wk,
    const float* __restrict__ Wv, const float* __restrict__ Wo,
    uint16_t* __restrict__ out)   // 4 mats contiguous, 262144 elems each
{
    const int z = blockIdx.z;
    const float* W = (z == 0) ? Wq : (z == 1) ? Wk : (z == 2) ? Wv : Wo;
    uint16_t* o = out + (size_t)z * 262144;
    const int n0 = blockIdx.x * 64, k0 = blockIdx.y * 64;
    __shared__ uint16_t tl[64][64];
    const int t = threadIdx.x;
    const int r  = t >> 4;
    const int c4 = (t & 15) * 4;
    #pragma unroll
    for (int s = 0; s < 4; ++s) {
        const int k = r + s * 16;
        float4 f = *(const float4*)(W + (size_t)(k0 + k) * 512 + n0 + c4);
        tl[c4 + 0][k] = f2b(f.x); tl[c4 + 1][k] = f2b(f.y);
        tl[c4 + 2][k] = f2b(f.z); tl[c4 + 3][k] = f2b(f.w);
    }
    __syncthreads();
    const int n  = t >> 2;
    const int kk = (t & 3) * 16;
    uint4* dst = (uint4*)(o + (size_t)(n0 + n) * 512 + k0 + kk);
    dst[0] = *(const uint4*)&tl[n][kk];
    dst[1] = *(const uint4*)&tl[n][kk + 8];
}

// ---------------------------------------------------------------------------
// Fused QKV projection, 128x128 tile, BK=32, full async A+B (zero staging
// VALU). Flat grid 3072, XCD-swizzled: id = 8*(12*(s>>3)+j) + (s&7) so the
// 12 blocks sharing Xb m-stripe s land on one XCD. j = proj*4 + n-tile.
// MFMA layouts (m89/m120): A[m=lane&15][k=quad*8+j]; B^T[n][k] lane=n;
// D: row=quad*4+r, col=lane&15.
// ---------------------------------------------------------------------------
__global__ __launch_bounds__(256) void qkv128(
    const uint16_t* __restrict__ Xb,
    const uint16_t* __restrict__ Wt,   // 3 mats [n][k] bf16
    const float* __restrict__ bq_, const float* __restrict__ bk_,
    const float* __restrict__ bv_,
    uint16_t* __restrict__ outQ, uint16_t* __restrict__ outK,
    uint16_t* __restrict__ outV)
{
    const int id = blockIdx.x;
    const int c  = id & 7;
    const int r_ = id >> 3;
    const int j_ = r_ % 12;
    const int s  = (r_ / 12) * 8 + c;     // m-stripe 0..255
    const int proj = j_ >> 2;
    const int n0   = (j_ & 3) * 128;
    const int m0   = s * 128;

    const uint16_t* W = Wt + (size_t)proj * 262144;
    const float* bias = (proj == 0) ? bq_ : (proj == 1) ? bk_ : bv_;
    uint16_t* out     = (proj == 0) ? outQ : (proj == 1) ? outK : outV;
    const int act = (proj < 2);

    __shared__ uint16_t sA[128 * 32];
    __shared__ uint16_t sB[128 * 32];
    const int t = threadIdx.x;
    const int wave = t >> 6, lane = t & 63, quad = lane >> 4, lrow = lane & 15;
    const int wm = (wave & 1) * 64, wn = (wave >> 1) * 64;
    const int sr = t >> 2;             // staging row 0..63
    const int sc = (t & 3) * 8;        // staging k-offset

    floatx4 acc[4][4] = {};

    for (int k0 = 0; k0 < 512; k0 += 32) {
        const uint16_t* gA = Xb + (size_t)(m0 + sr) * 512 + k0 + sc;
        async_copy16(gA, sA + t * 8);
        async_copy16(gA + 64 * 512, sA + (t + 256) * 8);
        const uint16_t* gB = W + (size_t)(n0 + sr) * 512 + k0 + sc;
        async_copy16(gB, sB + t * 8);
        async_copy16(gB + 64 * 512, sB + (t + 256) * 8);
        __syncthreads();
        bf16x8 af[4], bfr[4];
        #pragma unroll
        for (int i = 0; i < 4; ++i)
            af[i] = *(const bf16x8*)(sA + (wm + i * 16 + lrow) * 32 + quad * 8);
        #pragma unroll
        for (int j = 0; j < 4; ++j)
            bfr[j] = *(const bf16x8*)(sB + (wn + j * 16 + lrow) * 32 + quad * 8);
        #pragma unroll
        for (int i = 0; i < 4; ++i)
            #pragma unroll
            for (int j = 0; j < 4; ++j)
                acc[i][j] = __builtin_amdgcn_mfma_f32_16x16x32_bf16(af[i], bfr[j], acc[i][j], 0, 0, 0);
        __syncthreads();
    }

    #pragma unroll
    for (int j = 0; j < 4; ++j) {
        const int col = n0 + wn + j * 16 + lrow;
        const float bb = bias[col];
        #pragma unroll
        for (int i = 0; i < 4; ++i) {
            #pragma unroll
            for (int r = 0; r < 4; ++r) {
                const int row = m0 + wm + i * 16 + quad * 4 + r;
                float v = acc[i][j][r] + bb;
                if (act) v = (v > 0.0f) ? (v + 1.0f) : __expf(v);  // elu+1
                out[(size_t)row * 512 + col] = f2b(v);
            }
        }
    }
}

// ---------------------------------------------------------------------------
// Output projection, 128x128 tile. Flat grid 1024, XCD-swizzled:
// id = 8*(4*(s>>3)+j) + (s&7). A (bf16) and B (Wo^T bf16) both async-staged.
// out = A*Wo + bo + resid(fp32).
// ---------------------------------------------------------------------------
__global__ __launch_bounds__(256) void gemm_out128(
    const uint16_t* __restrict__ A,
    const uint16_t* __restrict__ Wt,   // [n][k] bf16
    const float* __restrict__ bias,
    const float* __restrict__ resid,
    uint16_t* __restrict__ out)
{
    const int id = blockIdx.x;
    const int c  = id & 7;
    const int r_ = id >> 3;
    const int j_ = r_ & 3;
    const int s  = (r_ >> 2) * 8 + c;
    const int n0 = j_ * 128;
    const int m0 = s * 128;

    __shared__ uint16_t sA[128 * 32];
    __shared__ uint16_t sB[128 * 32];
    const int t = threadIdx.x;
    const int wave = t >> 6, lane = t & 63, quad = lane >> 4, lrow = lane & 15;
    const int wm = (wave & 1) * 64, wn = (wave >> 1) * 64;
    const int sr = t >> 2;
    const int sc = (t & 3) * 8;

    floatx4 acc[4][4] = {};

    for (int k0 = 0; k0 < 512; k0 += 32) {
        const uint16_t* gA = A + (size_t)(m0 + sr) * 512 + k0 + sc;
        async_copy16(gA, sA + t * 8);
        async_copy16(gA + 64 * 512, sA + (t + 256) * 8);
        const uint16_t* gB = Wt + (size_t)(n0 + sr) * 512 + k0 + sc;
        async_copy16(gB, sB + t * 8);
        async_copy16(gB + 64 * 512, sB + (t + 256) * 8);
        __syncthreads();
        bf16x8 af[4], bfr[4];
        #pragma unroll
        for (int i = 0; i < 4; ++i)
            af[i] = *(const bf16x8*)(sA + (wm + i * 16 + lrow) * 32 + quad * 8);
        #pragma unroll
        for (int j = 0; j < 4; ++j)
            bfr[j] = *(const bf16x8*)(sB + (wn + j * 16 + lrow) * 32 + quad * 8);
        #pragma unroll
        for (int i = 0; i < 4; ++i)
            #pragma unroll
            for (int j = 0; j < 4; ++j)
                acc[i][j] = __builtin_amdgcn_mfma_f32_16x16x32_bf16(af[i], bfr[j], acc[i][j], 0, 0, 0);
        __syncthreads();
    }

    #pragma unroll
    for (int j = 0; j < 4; ++j) {
        const int col = n0 + wn + j * 16 + lrow;
        const float bb = bias[col];
        #pragma unroll
        for (int i = 0; i < 4; ++i) {
            #pragma unroll
            for (int r = 0; r < 4; ++r) {
                const int row = m0 + wm + i * 16 + quad * 4 + r;
                float v = acc[i][j][r] + bb + resid[(size_t)row * 512 + col];
                out[(size_t)row * 512 + col] = f2b(v);
            }
        }
    }
}

// ---------------------------------------------------------------------------
// KV[bh][d][m] += sum_n k[n][d]*v[n][m]  (MFMA: C = K^T * V, split-K atomics)
// KSUM[bh][d]  += sum_n k[n][d]          (MFMA with all-ones B)
// grid (16 chunks of 512 tokens, H, B).
// ---------------------------------------------------------------------------
__global__ __launch_bounds__(256) void kv_accum(
    const uint16_t* __restrict__ K,
    const uint16_t* __restrict__ V,
    float* __restrict__ KV,
    float* __restrict__ KSUM)
{
    const int chunk = blockIdx.x;
    const int h     = blockIdx.y;
    const int b     = blockIdx.z;
    const int t    = threadIdx.x;
    const int wv   = t >> 6;
    const int lane = t & 63;
    const int quad = lane >> 4;
    const int lrow = lane & 15;

    __shared__ uint16_t kt[64 * 72];   // [d][tok]
    __shared__ uint16_t vt[64 * 72];   // [m][tok]

    floatx4 acc[4] = {};
    floatx4 accS = {};
    union { uint16_t u[8]; bf16x8 v; } one_u;
    #pragma unroll
    for (int j = 0; j < 8; ++j) one_u.u[j] = 0x3F80;  // bf16 1.0
    const bf16x8 ones = one_u.v;

    const size_t base = ((size_t)(b * SEQ + chunk * 512)) * 512 + h * 64;

    for (int n0 = 0; n0 < 512; n0 += 64) {
        #pragma unroll
        for (int s = 0; s < 2; ++s) {
            const int i   = t + 256 * s;
            const int tok = i >> 3;
            const int d0  = (i & 7) * 8;
            uint4 kq = *(const uint4*)(K + base + (size_t)(n0 + tok) * 512 + d0);
            const uint16_t* kp = (const uint16_t*)&kq;
            #pragma unroll
            for (int j = 0; j < 8; ++j) kt[(d0 + j) * 72 + tok] = kp[j];
            uint4 vq = *(const uint4*)(V + base + (size_t)(n0 + tok) * 512 + d0);
            const uint16_t* vp = (const uint16_t*)&vq;
            #pragma unroll
            for (int j = 0; j < 8; ++j) vt[(d0 + j) * 72 + tok] = vp[j];
        }
        __syncthreads();
        #pragma unroll
        for (int ks = 0; ks < 2; ++ks) {
            bf16x8 af = *(const bf16x8*)(kt + (wv * 16 + lrow) * 72 + ks * 32 + quad * 8);
            accS = __builtin_amdgcn_mfma_f32_16x16x32_bf16(af, ones, accS, 0, 0, 0);
            #pragma unroll
            for (int nt = 0; nt < 4; ++nt) {
                bf16x8 bf = *(const bf16x8*)(vt + (nt * 16 + lrow) * 72 + ks * 32 + quad * 8);
                acc[nt] = __builtin_amdgcn_mfma_f32_16x16x32_bf16(af, bf, acc[nt], 0, 0, 0);
            }
        }
        __syncthreads();
    }

    float* kvp = KV + (size_t)(b * NHEAD + h) * 4096;
    #pragma unroll
    for (int nt = 0; nt < 4; ++nt) {
        const int m = nt * 16 + lrow;
        #pragma unroll
        for (int r = 0; r < 4; ++r) {
            const int d = wv * 16 + quad * 4 + r;
            atomicAdd(kvp + d * 64 + m, acc[nt][r]);
        }
    }
    if (lrow == 0) {
        float* kp = KSUM + (size_t)(b * NHEAD + h) * 64;
        #pragma unroll
        for (int r = 0; r < 4; ++r)
            atomicAdd(kp + wv * 16 + quad * 4 + r, accS[r]);
    }
}

// ---------------------------------------------------------------------------
// out[n][h*64+m] = (sum_d q[n][d]*KV[d][m]) / max(sum_d q[n][d]*ksum[d],1e-6)
// grid (NTOK/64, H).
// ---------------------------------------------------------------------------
__global__ __launch_bounds__(256) void attn_apply(
    const uint16_t* __restrict__ Q,
    const float* __restrict__ KVg,
    const float* __restrict__ KSg,
    uint16_t* __restrict__ OUT)
{
    const int h    = blockIdx.y;
    const int tok0 = blockIdx.x * 64;
    const int b    = tok0 >> 13;       // /8192, blocks never straddle batches
    const int t    = threadIdx.x;
    const int wv   = t >> 6;
    const int lane = t & 63;
    const int quad = lane >> 4;
    const int lrow = lane & 15;

    __shared__ uint16_t bt[64 * 72];   // [m][d] = KV^T, bf16
    __shared__ uint16_t ksb[64];

    const float* kvp = KVg + (size_t)(b * NHEAD + h) * 4096;
    #pragma unroll
    for (int s = 0; s < 16; ++s) {
        const int e = t + 256 * s;     // e = d*64 + m
        const int d = e >> 6, m = e & 63;
        bt[m * 72 + d] = f2b(kvp[e]);
    }
    if (t < 64) ksb[t] = f2b(KSg[(size_t)(b * NHEAD + h) * 64 + t]);
    __syncthreads();

    floatx4 acc[4] = {};
    floatx4 accN = {};
    const uint16_t* qrow = Q + (size_t)(tok0 + wv * 16 + lrow) * 512 + h * 64 + quad * 8;
    #pragma unroll
    for (int ks = 0; ks < 2; ++ks) {
        bf16x8 af = *(const bf16x8*)(qrow + ks * 32);
        bf16x8 bks = *(const bf16x8*)(ksb + ks * 32 + quad * 8);
        accN = __builtin_amdgcn_mfma_f32_16x16x32_bf16(af, bks, accN, 0, 0, 0);
        #pragma unroll
        for (int nt = 0; nt < 4; ++nt) {
            bf16x8 bf = *(const bf16x8*)(bt + (nt * 16 + lrow) * 72 + ks * 32 + quad * 8);
            acc[nt] = __builtin_amdgcn_mfma_f32_16x16x32_bf16(af, bf, acc[nt], 0, 0, 0);
        }
    }

    #pragma unroll
    for (int r = 0; r < 4; ++r) {
        const float inv = 1.0f / fmaxf(accN[r], 1e-6f);
        const int tok = tok0 + wv * 16 + quad * 4 + r;
        #pragma unroll
        for (int nt = 0; nt < 4; ++nt)
            OUT[(size_t)tok * 512 + h * 64 + nt * 16 + lrow] = f2b(acc[nt][r] * inv);
    }
}

// rowwise LayerNorm over 512: Z bf16, gamma/beta fp32, OUT fp32.
__global__ __launch_bounds__(256) void ln_fused(
    const uint16_t* __restrict__ Z,
    const float* __restrict__ gamma,
    const float* __restrict__ beta,
    float* __restrict__ OUT)
{
    const size_t row = blockIdx.x;
    const int t = threadIdx.x;
    const uint16_t* zp = Z + row * 512;
    uint32_t u = *(const uint32_t*)(zp + t * 2);
    float v0 = b2f((uint16_t)(u & 0xffff));
    float v1 = b2f((uint16_t)(u >> 16));
    float s = v0 + v1;
    float s2 = v0 * v0 + v1 * v1;
    #pragma unroll
    for (int off = 32; off > 0; off >>= 1) {
        s  += __shfl_down(s, off, 64);
        s2 += __shfl_down(s2, off, 64);
    }
    __shared__ float sb[4], sb2[4];
    const int wv = t >> 6, lane = t & 63;
    if (lane == 0) { sb[wv] = s; sb2[wv] = s2; }
    __syncthreads();
    const float tot  = sb[0] + sb[1] + sb[2] + sb[3];
    const float tot2 = sb2[0] + sb2[1] + sb2[2] + sb2[3];
    const float mean = tot * (1.0f / 512.0f);
    const float var  = tot2 * (1.0f / 512.0f) - mean * mean;
    const float inv  = rsqrtf(var + 1e-5f);
    const float2 g  = *(const float2*)(gamma + t * 2);
    const float2 bb = *(const float2*)(beta + t * 2);
    float2 o;
    o.x = (v0 - mean) * inv * g.x + bb.x;
    o.y = (v1 - mean) * inv * g.y + bb.y;
    *(float2*)(OUT + row * 512 + t * 2) = o;
}

extern "C" void kernel_launch(void* const* d_in, const int* in_sizes, int n_in,
                              void* d_out, int out_size, void* d_ws, size_t ws_size,
                              hipStream_t stream)
{
    (void)in_sizes; (void)n_in; (void)out_size; (void)ws_size;
    const float* x     = (const float*)d_in[0];
    const float* Wq    = (const float*)d_in[1];
    const float* bq    = (const float*)d_in[2];
    const float* Wk    = (const float*)d_in[3];
    const float* bk    = (const float*)d_in[4];
    const float* Wv    = (const float*)d_in[5];
    const float* bv    = (const float*)d_in[6];
    const float* Wo    = (const float*)d_in[7];
    const float* bo    = (const float*)d_in[8];
    const float* gamma = (const float*)d_in[9];
    const float* beta  = (const float*)d_in[10];

    // ws layout (~66.6 MiB): KV(512K) + KSUM(8K) + Wt(2M) + phiQ(32M) + Xb(32M).
    // d_out (fp32, 64 MiB) doubles as bf16 scratch until the final LN write:
    //   low half: phiK -> attn ; high half: vbuf.
    uint8_t* ws = (uint8_t*)d_ws;
    float*    KV   = (float*)ws;
    float*    KSUM = (float*)(ws + (size_t)32 * 4096 * 4);
    uint16_t* Wt   = (uint16_t*)(ws + (size_t)32 * 4096 * 4 + 32 * 64 * 4);
    uint16_t* phiQ = (uint16_t*)(ws + (size_t)32 * 4096 * 4 + 32 * 64 * 4
                                    + (size_t)4 * 262144 * 2);
    uint16_t* Xb   = phiQ + (size_t)NTOK * 512;
    uint16_t* phiK = (uint16_t*)d_out;
    uint16_t* vbuf = (uint16_t*)d_out + (size_t)NTOK * 512;
    uint16_t* attn = phiK;   // phiK dead after kv_accum
    uint16_t* zbuf = phiQ;   // phiQ dead after attn_apply

    hipMemsetAsync(ws, 0, (size_t)32 * 4096 * 4 + 32 * 64 * 4, stream);

    dim3 blk(256);
    convert_x<<<dim3(NTOK * 512 / (256 * 8)), blk, 0, stream>>>(x, Xb);
    convert_w<<<dim3(8, 8, 4), blk, 0, stream>>>(Wq, Wk, Wv, Wo, Wt);
    qkv128<<<dim3(3072), blk, 0, stream>>>(
        Xb, Wt, bq, bk, bv, phiQ, phiK, vbuf);
    kv_accum<<<dim3(16, NHEAD, BATCH), blk, 0, stream>>>(phiK, vbuf, KV, KSUM);
    attn_apply<<<dim3(NTOK / 64, NHEAD), blk, 0, stream>>>(phiQ, KV, KSUM, attn);
    gemm_out128<<<dim3(1024), blk, 0, stream>>>(
        attn, Wt + (size_t)3 * 262144, bo, x, zbuf);
    ln_fused<<<NTOK, blk, 0, stream>>>(zbuf, gamma, beta, (float*)d_out);
}